// Round 2
// baseline (3256.845 us; speedup 1.0000x reference)
//
#include <hip/hip_runtime.h>
#include <math.h>

#define N_NODES 100000
#define N_EDGES 400000
#define HID 128
#define HEADS 4
#define OUT_C 64
#define HD 256   // HEADS*OUT_C

// ---------- helpers: order-preserving float<->uint for atomicMax ----------
__device__ __forceinline__ unsigned fenc(float f) {
    unsigned b = __float_as_uint(f);
    return (b & 0x80000000u) ? ~b : (b | 0x80000000u);
}
__device__ __forceinline__ float fdec(unsigned u) {
    return (u & 0x80000000u) ? __uint_as_float(u ^ 0x80000000u)
                             : __uint_as_float(~u);
}

// ---------- K0: zero-init segment buffers (replaces hipMemsetAsync) ----------
__global__ __launch_bounds__(256) void init_seg(unsigned* __restrict__ smaxu,
                                                float* __restrict__ denom) {
    int i = blockIdx.x * 256 + threadIdx.x;
    if (i < N_NODES * 4) { smaxu[i] = 0u; denom[i] = 0.f; }
}

// ---------- K1: one projection GEMM;  h = x+memory computed on the fly ----------
// O = (x+mem) @ W + b,  M=100000, K=128, N=256
// BM=64, BN=64, BK staged in 2 chunks of 64. 256 thr, 4x4 microtile/thread.
__global__ __launch_bounds__(256) void node_gemm(
    const float* __restrict__ x, const float* __restrict__ mem,
    const float* __restrict__ W, const float* __restrict__ bias,
    float* __restrict__ O)
{
    __shared__ float As[64 * 130];   // 64 rows x 128 cols, pad->130
    __shared__ float Bs[64 * 64];    // 64 k-rows x 64 cols

    const int t  = threadIdx.x;
    const int m0 = blockIdx.x * 64;
    const int n0 = blockIdx.y * 64;

    // stage A tile: (x+mem)[m0..m0+64, 0..128)
    {
        const float4* x4 = (const float4*)x;
        const float4* m4 = (const float4*)mem;
#pragma unroll
        for (int j = 0; j < 8; ++j) {
            int idx = t + j * 256;       // float4 index, 64*32 = 2048 total
            int row = idx >> 5;
            int c4  = idx & 31;
            int gr  = m0 + row;
            float4 val = make_float4(0.f, 0.f, 0.f, 0.f);
            if (gr < N_NODES) {
                float4 a = x4[gr * 32 + c4];
                float4 b = m4[gr * 32 + c4];
                val = make_float4(a.x + b.x, a.y + b.y, a.z + b.z, a.w + b.w);
            }
            float* dst = &As[row * 130 + c4 * 4];
            dst[0] = val.x; dst[1] = val.y; dst[2] = val.z; dst[3] = val.w;
        }
    }

    const int tx = t & 15;   // col group (4 cols)
    const int ty = t >> 4;   // row group (4 rows)
    float acc[4][4] = {{0.f}};

    for (int kc = 0; kc < 2; ++kc) {
        __syncthreads();
        // stage B chunk: W[kc*64 .. +64, n0..n0+64)
#pragma unroll
        for (int j = 0; j < 4; ++j) {
            int idx = t + j * 256;       // float4 idx, 64*16 = 1024 total
            int kk  = idx >> 4;
            int c4  = idx & 15;
            *(float4*)&Bs[kk * 64 + c4 * 4] =
                *(const float4*)&W[(kc * 64 + kk) * HD + n0 + c4 * 4];
        }
        __syncthreads();
#pragma unroll 8
        for (int kk = 0; kk < 64; ++kk) {
            int kg = kc * 64 + kk;
            float a0 = As[(ty * 4 + 0) * 130 + kg];
            float a1 = As[(ty * 4 + 1) * 130 + kg];
            float a2 = As[(ty * 4 + 2) * 130 + kg];
            float a3 = As[(ty * 4 + 3) * 130 + kg];
            float4 b = *(const float4*)&Bs[kk * 64 + tx * 4];
            acc[0][0] += a0 * b.x; acc[0][1] += a0 * b.y; acc[0][2] += a0 * b.z; acc[0][3] += a0 * b.w;
            acc[1][0] += a1 * b.x; acc[1][1] += a1 * b.y; acc[1][2] += a1 * b.z; acc[1][3] += a1 * b.w;
            acc[2][0] += a2 * b.x; acc[2][1] += a2 * b.y; acc[2][2] += a2 * b.z; acc[2][3] += a2 * b.w;
            acc[3][0] += a3 * b.x; acc[3][1] += a3 * b.y; acc[3][2] += a3 * b.z; acc[3][3] += a3 * b.w;
        }
    }

    float4 bb = *(const float4*)&bias[n0 + tx * 4];
#pragma unroll
    for (int r = 0; r < 4; ++r) {
        int gr = m0 + ty * 4 + r;
        if (gr < N_NODES) {
            float4 val = make_float4(acc[r][0] + bb.x, acc[r][1] + bb.y,
                                     acc[r][2] + bb.z, acc[r][3] + bb.w);
            *(float4*)&O[(size_t)gr * HD + n0 + tx * 4] = val;
        }
    }
}

// ---------- K2: per-edge scores + segment max ----------
// one 64-lane wave per edge; lane l covers dims 4l..4l+3; head = l/16
__global__ __launch_bounds__(256) void edge_scores(
    const int* __restrict__ ei, const float* __restrict__ q,
    const float* __restrict__ k, float* __restrict__ scores,
    unsigned* __restrict__ smaxu)
{
    int e = blockIdx.x * 4 + (threadIdx.x >> 6);
    int l = threadIdx.x & 63;
    if (e >= N_EDGES) return;
    int src = ei[e];
    int dst = ei[N_EDGES + e];
    float4 qq = *(const float4*)&q[(size_t)dst * HD + l * 4];
    float4 kk = *(const float4*)&k[(size_t)src * HD + l * 4];
    float s = qq.x * kk.x + qq.y * kk.y + qq.z * kk.z + qq.w * kk.w;
    s += __shfl_xor(s, 1);
    s += __shfl_xor(s, 2);
    s += __shfl_xor(s, 4);
    s += __shfl_xor(s, 8);
    s *= 0.125f;                       // 1/sqrt(64)
    int h = l >> 4;
    if ((l & 15) == 0) {
        scores[e * 4 + h] = s;
        atomicMax(&smaxu[dst * 4 + h], fenc(s));
    }
}

// ---------- K3: e = exp(s - smax[dst]);  denom += e ----------
__global__ __launch_bounds__(256) void edge_exp(
    const int* __restrict__ ei, float* __restrict__ scores,
    const unsigned* __restrict__ smaxu, float* __restrict__ denom)
{
    int i = blockIdx.x * 256 + threadIdx.x;
    if (i >= N_EDGES * 4) return;
    int e = i >> 2, h = i & 3;
    int dst = ei[N_EDGES + e];
    float m  = fdec(smaxu[dst * 4 + h]);
    float ev = __expf(scores[i] - m);
    scores[i] = ev;
    atomicAdd(&denom[dst * 4 + h], ev);
}

// ---------- K4: out[dst] += alpha * v[src]  (atomic) ----------
__global__ __launch_bounds__(256) void edge_agg(
    const int* __restrict__ ei, const float* __restrict__ scores,
    const float* __restrict__ denom, const float* __restrict__ v,
    float* __restrict__ out)
{
    int e = blockIdx.x * 4 + (threadIdx.x >> 6);
    int l = threadIdx.x & 63;
    if (e >= N_EDGES) return;
    int src = ei[e];
    int dst = ei[N_EDGES + e];
    int h = l >> 4;
    float a = scores[e * 4 + h] / (denom[dst * 4 + h] + 1e-16f);
    float4 vv = *(const float4*)&v[(size_t)src * HD + l * 4];
    float* op = &out[(size_t)dst * HD + l * 4];
    atomicAdd(op + 0, a * vv.x);
    atomicAdd(op + 1, a * vv.y);
    atomicAdd(op + 2, a * vv.z);
    atomicAdd(op + 3, a * vv.w);
}

// ---------- K5: fused rating MLP, 32 edges/block ----------
// layer1 [32,512]@[512,128], staged in 2 phases of 256 cols (src-half, dst-half)
__global__ __launch_bounds__(256) void edge_mlp(
    const int* __restrict__ ei, const float* __restrict__ out,
    const float* __restrict__ W1, const float* __restrict__ b1,
    const float* __restrict__ W2, const float* __restrict__ b2,
    const float* __restrict__ W3, const float* __restrict__ b3,
    float* __restrict__ rating)
{
    __shared__ float inter_s[32 * 256];  // 32 KB: one 256-wide phase of inter
    __shared__ float h1[32 * 132];       // 16.9 KB (pad 132)
    __shared__ float h2[32 * 68];        // 8.7 KB (pad 68)

    const int t  = threadIdx.x;
    const int e0 = blockIdx.x * 32;

    const int tx = t & 31;   // layer1 col group: cols 4tx..4tx+3 (of 128)
    const int ty = t >> 5;   // layer1 row group: rows 4ty..4ty+3 (of 32)
    float acc[4][4] = {{0.f}};

    for (int p = 0; p < 2; ++p) {
        // stage: rows = edges, 256 cols = out[src] (p=0) or out[dst] (p=1)
#pragma unroll
        for (int j = 0; j < 8; ++j) {
            int idx  = t + j * 256;   // float4 idx, 32*64 = 2048
            int row  = idx >> 6;
            int c4   = idx & 63;
            int node = ei[p * N_EDGES + e0 + row];
            *(float4*)&inter_s[row * 256 + c4 * 4] =
                *(const float4*)&out[(size_t)node * HD + c4 * 4];
        }
        __syncthreads();
#pragma unroll 4
        for (int kk = 0; kk < 256; ++kk) {
            float4 w = *(const float4*)&W1[(p * 256 + kk) * 128 + tx * 4];
            float a0 = inter_s[(ty * 4 + 0) * 256 + kk];
            float a1 = inter_s[(ty * 4 + 1) * 256 + kk];
            float a2 = inter_s[(ty * 4 + 2) * 256 + kk];
            float a3 = inter_s[(ty * 4 + 3) * 256 + kk];
            acc[0][0] += a0 * w.x; acc[0][1] += a0 * w.y; acc[0][2] += a0 * w.z; acc[0][3] += a0 * w.w;
            acc[1][0] += a1 * w.x; acc[1][1] += a1 * w.y; acc[1][2] += a1 * w.z; acc[1][3] += a1 * w.w;
            acc[2][0] += a2 * w.x; acc[2][1] += a2 * w.y; acc[2][2] += a2 * w.z; acc[2][3] += a2 * w.w;
            acc[3][0] += a3 * w.x; acc[3][1] += a3 * w.y; acc[3][2] += a3 * w.z; acc[3][3] += a3 * w.w;
        }
        __syncthreads();
    }

    // bias + relu -> h1
    {
        float4 bb = *(const float4*)&b1[tx * 4];
        float bv[4] = {bb.x, bb.y, bb.z, bb.w};
#pragma unroll
        for (int r = 0; r < 4; ++r)
#pragma unroll
            for (int c = 0; c < 4; ++c)
                h1[(ty * 4 + r) * 132 + tx * 4 + c] = fmaxf(acc[r][c] + bv[c], 0.f);
    }
    __syncthreads();

    // layer2: [32,128]@[128,64]; 2 rows x 4 cols per thread
    const int tx2 = t & 15;  // cols 4tx2..4tx2+3 (of 64)
    const int ty2 = t >> 4;  // rows 2ty2..2ty2+1 (of 32)
    float acc2[2][4] = {{0.f}};
#pragma unroll 8
    for (int kk = 0; kk < 128; ++kk) {
        float4 w = *(const float4*)&W2[kk * 64 + tx2 * 4];
        float a0 = h1[(ty2 * 2 + 0) * 132 + kk];
        float a1 = h1[(ty2 * 2 + 1) * 132 + kk];
        acc2[0][0] += a0 * w.x; acc2[0][1] += a0 * w.y; acc2[0][2] += a0 * w.z; acc2[0][3] += a0 * w.w;
        acc2[1][0] += a1 * w.x; acc2[1][1] += a1 * w.y; acc2[1][2] += a1 * w.z; acc2[1][3] += a1 * w.w;
    }
    {
        float4 bb = *(const float4*)&b2[tx2 * 4];
        float bv[4] = {bb.x, bb.y, bb.z, bb.w};
#pragma unroll
        for (int i = 0; i < 2; ++i)
#pragma unroll
            for (int c = 0; c < 4; ++c)
                h2[(ty2 * 2 + i) * 68 + tx2 * 4 + c] = fmaxf(acc2[i][c] + bv[c], 0.f);
    }
    __syncthreads();

    // layer3: [32,64]@[64,1] -> sigmoid*4+1
    if (t < 32) {
        float a = b3[0];
#pragma unroll 8
        for (int kk = 0; kk < 64; ++kk)
            a += h2[t * 68 + kk] * W3[kk];
        int e = e0 + t;
        if (e < N_EDGES)
            rating[e] = 4.f / (1.f + __expf(-a)) + 1.f;
    }
}

extern "C" void kernel_launch(void* const* d_in, const int* in_sizes, int n_in,
                              void* d_out, int out_size, void* d_ws, size_t ws_size,
                              hipStream_t stream) {
    const int*   ei  = (const int*)d_in[0];    // [2, E]
    // d_in[1] = edge_time (unused by reference)
    const float* x   = (const float*)d_in[2];
    const float* mem = (const float*)d_in[3];
    const float* Wq  = (const float*)d_in[4];
    const float* bq  = (const float*)d_in[5];
    const float* Wk  = (const float*)d_in[6];
    const float* bk  = (const float*)d_in[7];
    const float* Wv  = (const float*)d_in[8];
    const float* bv  = (const float*)d_in[9];
    const float* Ws  = (const float*)d_in[10];
    const float* bs  = (const float*)d_in[11];
    const float* W1  = (const float*)d_in[12];
    const float* b1  = (const float*)d_in[13];
    const float* W2  = (const float*)d_in[14];
    const float* b2  = (const float*)d_in[15];
    const float* W3  = (const float*)d_in[16];
    const float* b3  = (const float*)d_in[17];
    float* rating = (float*)d_out;

    // Workspace layout (214.4 MB total):
    //   A [N,256] f32: q, later v        (102.4 MB)
    //   B [N,256] f32: k, later skip+agg (102.4 MB)
    //   scores [E,4] f32                 (6.4 MB)
    //   smaxu  [N,4] u32                 (1.6 MB)
    //   denom  [N,4] f32                 (1.6 MB)
    float* ws = (float*)d_ws;
    const size_t NHD = (size_t)N_NODES * HD;   // 25.6M
    float*    A      = ws;
    float*    B      = A + NHD;
    float*    scores = B + NHD;
    unsigned* smaxu  = (unsigned*)(scores + (size_t)N_EDGES * 4);
    float*    denom  = (float*)(smaxu + (size_t)N_NODES * 4);

    const dim3 ggrid((N_NODES + 63) / 64, HD / 64);

    init_seg<<<(N_NODES * 4 + 255) / 256, 256, 0, stream>>>(smaxu, denom);
    node_gemm<<<ggrid, 256, 0, stream>>>(x, mem, Wq, bq, A);   // A = q
    node_gemm<<<ggrid, 256, 0, stream>>>(x, mem, Wk, bk, B);   // B = k
    edge_scores<<<(N_EDGES + 3) / 4, 256, 0, stream>>>(ei, A, B, scores, smaxu);
    node_gemm<<<ggrid, 256, 0, stream>>>(x, mem, Wv, bv, A);   // A = v (q dead)
    node_gemm<<<ggrid, 256, 0, stream>>>(x, mem, Ws, bs, B);   // B = skip (k dead)
    edge_exp<<<(N_EDGES * 4 + 255) / 256, 256, 0, stream>>>(ei, scores, smaxu, denom);
    edge_agg<<<(N_EDGES + 3) / 4, 256, 0, stream>>>(ei, scores, denom, A, B);
    edge_mlp<<<(N_EDGES + 31) / 32, 256, 0, stream>>>(
        ei, B, W1, b1, W2, b2, W3, b3, rating);
}

// Round 3
// 2020.484 us; speedup vs baseline: 1.6119x; 1.6119x over previous
//
#include <hip/hip_runtime.h>
#include <math.h>

#define N_NODES 100000
#define N_EDGES 400000
#define HID 128
#define HEADS 4
#define OUT_C 64
#define HD 256   // HEADS*OUT_C
#define SCAN_CHUNK 1024
#define NB_SCAN ((N_NODES + SCAN_CHUNK - 1) / SCAN_CHUNK)   // 98

// ---------- K0: zero deg + cursor ----------
__global__ __launch_bounds__(256) void init_zero(int* __restrict__ deg,
                                                 int* __restrict__ cursor) {
    int i = blockIdx.x * 256 + threadIdx.x;
    if (i < N_NODES) { deg[i] = 0; cursor[i] = 0; }
}

// ---------- CSR build: degree count ----------
__global__ __launch_bounds__(256) void k_deg(const int* __restrict__ ei,
                                             int* __restrict__ deg) {
    int e = blockIdx.x * 256 + threadIdx.x;
    if (e < N_EDGES) atomicAdd(&deg[ei[N_EDGES + e]], 1);
}

// ---------- scan 1: per-block (1024 elems) exclusive scan + block sums ----------
__global__ __launch_bounds__(256) void k_scan1(const int* __restrict__ deg,
                                               int* __restrict__ rp,
                                               int* __restrict__ bsum) {
    __shared__ int ts[256];
    int b = blockIdx.x, t = threadIdx.x;
    int base = b * SCAN_CHUNK + t * 4;
    int vv[4];
    int s = 0;
#pragma unroll
    for (int i = 0; i < 4; ++i) {
        int d = (base + i < N_NODES) ? deg[base + i] : 0;
        vv[i] = s;        // exclusive within the 4
        s += d;
    }
    ts[t] = s;
    __syncthreads();
    for (int off = 1; off < 256; off <<= 1) {
        int x = (t >= off) ? ts[t - off] : 0;
        __syncthreads();
        ts[t] += x;
        __syncthreads();
    }
    int ex = ts[t] - s;   // exclusive thread offset within block
#pragma unroll
    for (int i = 0; i < 4; ++i)
        if (base + i < N_NODES) rp[base + i] = ex + vv[i];
    if (t == 255) bsum[b] = ts[255];
}

// ---------- scan 2: single block scans the 98 block sums (exclusive) ----------
__global__ __launch_bounds__(256) void k_scan2(int* __restrict__ bsum) {
    __shared__ int ts[256];
    int t = threadIdx.x;
    int v = (t < NB_SCAN) ? bsum[t] : 0;
    ts[t] = v;
    __syncthreads();
    for (int off = 1; off < 256; off <<= 1) {
        int x = (t >= off) ? ts[t - off] : 0;
        __syncthreads();
        ts[t] += x;
        __syncthreads();
    }
    if (t < NB_SCAN) bsum[t] = ts[t] - v;   // exclusive
}

// ---------- scan 3: add block offsets ----------
__global__ __launch_bounds__(256) void k_scan3(int* __restrict__ rp,
                                               const int* __restrict__ bsum) {
    int i = blockIdx.x * 256 + threadIdx.x;
    if (i < N_NODES) rp[i] += bsum[i / SCAN_CHUNK];
}

// ---------- bucket: fill csr_src ----------
__global__ __launch_bounds__(256) void k_bucket(const int* __restrict__ ei,
                                                const int* __restrict__ rp,
                                                int* __restrict__ cursor,
                                                int* __restrict__ csr_src) {
    int e = blockIdx.x * 256 + threadIdx.x;
    if (e >= N_EDGES) return;
    int src = ei[e];
    int d   = ei[N_EDGES + e];
    int idx = atomicAdd(&cursor[d], 1);
    csr_src[rp[d] + idx] = src;
}

// ---------- K1: one projection GEMM;  h = x+memory computed on the fly ----------
// O = (x+mem) @ W + b,  M=100000, K=128, N=256
__global__ __launch_bounds__(256) void node_gemm(
    const float* __restrict__ x, const float* __restrict__ mem,
    const float* __restrict__ W, const float* __restrict__ bias,
    float* __restrict__ O)
{
    __shared__ float As[64 * 130];
    __shared__ float Bs[64 * 64];

    const int t  = threadIdx.x;
    const int m0 = blockIdx.x * 64;
    const int n0 = blockIdx.y * 64;

    {
        const float4* x4 = (const float4*)x;
        const float4* m4 = (const float4*)mem;
#pragma unroll
        for (int j = 0; j < 8; ++j) {
            int idx = t + j * 256;
            int row = idx >> 5;
            int c4  = idx & 31;
            int gr  = m0 + row;
            float4 val = make_float4(0.f, 0.f, 0.f, 0.f);
            if (gr < N_NODES) {
                float4 a = x4[gr * 32 + c4];
                float4 b = m4[gr * 32 + c4];
                val = make_float4(a.x + b.x, a.y + b.y, a.z + b.z, a.w + b.w);
            }
            float* dst = &As[row * 130 + c4 * 4];
            dst[0] = val.x; dst[1] = val.y; dst[2] = val.z; dst[3] = val.w;
        }
    }

    const int tx = t & 15;
    const int ty = t >> 4;
    float acc[4][4] = {{0.f}};

    for (int kc = 0; kc < 2; ++kc) {
        __syncthreads();
#pragma unroll
        for (int j = 0; j < 4; ++j) {
            int idx = t + j * 256;
            int kk  = idx >> 4;
            int c4  = idx & 15;
            *(float4*)&Bs[kk * 64 + c4 * 4] =
                *(const float4*)&W[(kc * 64 + kk) * HD + n0 + c4 * 4];
        }
        __syncthreads();
#pragma unroll 8
        for (int kk = 0; kk < 64; ++kk) {
            int kg = kc * 64 + kk;
            float a0 = As[(ty * 4 + 0) * 130 + kg];
            float a1 = As[(ty * 4 + 1) * 130 + kg];
            float a2 = As[(ty * 4 + 2) * 130 + kg];
            float a3 = As[(ty * 4 + 3) * 130 + kg];
            float4 b = *(const float4*)&Bs[kk * 64 + tx * 4];
            acc[0][0] += a0 * b.x; acc[0][1] += a0 * b.y; acc[0][2] += a0 * b.z; acc[0][3] += a0 * b.w;
            acc[1][0] += a1 * b.x; acc[1][1] += a1 * b.y; acc[1][2] += a1 * b.z; acc[1][3] += a1 * b.w;
            acc[2][0] += a2 * b.x; acc[2][1] += a2 * b.y; acc[2][2] += a2 * b.z; acc[2][3] += a2 * b.w;
            acc[3][0] += a3 * b.x; acc[3][1] += a3 * b.y; acc[3][2] += a3 * b.z; acc[3][3] += a3 * b.w;
        }
    }

    float4 bb = *(const float4*)&bias[n0 + tx * 4];
#pragma unroll
    for (int r = 0; r < 4; ++r) {
        int gr = m0 + ty * 4 + r;
        if (gr < N_NODES) {
            float4 val = make_float4(acc[r][0] + bb.x, acc[r][1] + bb.y,
                                     acc[r][2] + bb.z, acc[r][3] + bb.w);
            *(float4*)&O[(size_t)gr * HD + n0 + tx * 4] = val;
        }
    }
}

// ---------- K2: per-dst-node scores via CSR (no atomics) ----------
// one wave per node; lane l covers dims 4l..4l+3; head = l>>4
// pass1: s = q[dst]·k[src] per head -> scores; track m
// pass2: e = exp(s-m) -> scores;  denom -> denomArr
__global__ __launch_bounds__(256) void k_scores_csr(
    const int* __restrict__ rp, const int* __restrict__ deg,
    const int* __restrict__ csr_src,
    const float* __restrict__ q, const float* __restrict__ k,
    float* __restrict__ scores, float* __restrict__ denomArr)
{
    int node = blockIdx.x * 4 + (threadIdx.x >> 6);
    int l = threadIdx.x & 63;
    if (node >= N_NODES) return;
    int h     = l >> 4;
    int start = rp[node];
    int cnt   = deg[node];

    float4 qq = *(const float4*)&q[(size_t)node * HD + l * 4];

    float m = -1e30f;
    for (int i = 0; i < cnt; ++i) {
        int slot = start + i;
        int src  = csr_src[slot];
        float4 kk = *(const float4*)&k[(size_t)src * HD + l * 4];
        float s = qq.x * kk.x + qq.y * kk.y + qq.z * kk.z + qq.w * kk.w;
        s += __shfl_xor(s, 1);
        s += __shfl_xor(s, 2);
        s += __shfl_xor(s, 4);
        s += __shfl_xor(s, 8);
        s *= 0.125f;                    // 1/sqrt(64)
        if ((l & 15) == 0) scores[slot * 4 + h] = s;
        m = fmaxf(m, s);
    }
    float denom = 0.f;
    for (int i = 0; i < cnt; ++i) {
        int slot = start + i;
        float s  = scores[slot * 4 + h];
        float ev = __expf(s - m);
        if ((l & 15) == 0) scores[slot * 4 + h] = ev;
        denom += ev;
    }
    if ((l & 15) == 0) denomArr[node * 4 + h] = denom;
}

// ---------- K3: per-dst-node aggregation via CSR (no atomics) ----------
// out[dst] = skip[dst] + (sum_e e*v[src]) / denom
__global__ __launch_bounds__(256) void k_agg_csr(
    const int* __restrict__ rp, const int* __restrict__ deg,
    const int* __restrict__ csr_src,
    const float* __restrict__ scores, const float* __restrict__ denomArr,
    const float* __restrict__ v, float* __restrict__ out)
{
    int node = blockIdx.x * 4 + (threadIdx.x >> 6);
    int l = threadIdx.x & 63;
    if (node >= N_NODES) return;
    int h     = l >> 4;
    int start = rp[node];
    int cnt   = deg[node];

    float4 acc = make_float4(0.f, 0.f, 0.f, 0.f);
    for (int i = 0; i < cnt; ++i) {
        int slot = start + i;
        int src  = csr_src[slot];
        float e  = scores[slot * 4 + h];
        float4 vv = *(const float4*)&v[(size_t)src * HD + l * 4];
        acc.x += e * vv.x; acc.y += e * vv.y; acc.z += e * vv.z; acc.w += e * vv.w;
    }
    float inv = 1.f / (denomArr[node * 4 + h] + 1e-16f);
    float* op = &out[(size_t)node * HD + l * 4];
    float4 sk = *(const float4*)op;
    float4 res = make_float4(sk.x + acc.x * inv, sk.y + acc.y * inv,
                             sk.z + acc.z * inv, sk.w + acc.w * inv);
    *(float4*)op = res;
}

// ---------- K5: fused rating MLP, 32 edges/block ----------
__global__ __launch_bounds__(256) void edge_mlp(
    const int* __restrict__ ei, const float* __restrict__ out,
    const float* __restrict__ W1, const float* __restrict__ b1,
    const float* __restrict__ W2, const float* __restrict__ b2,
    const float* __restrict__ W3, const float* __restrict__ b3,
    float* __restrict__ rating)
{
    __shared__ float inter_s[32 * 256];
    __shared__ float h1[32 * 132];
    __shared__ float h2[32 * 68];

    const int t  = threadIdx.x;
    const int e0 = blockIdx.x * 32;

    const int tx = t & 31;
    const int ty = t >> 5;
    float acc[4][4] = {{0.f}};

    for (int p = 0; p < 2; ++p) {
#pragma unroll
        for (int j = 0; j < 8; ++j) {
            int idx  = t + j * 256;
            int row  = idx >> 6;
            int c4   = idx & 63;
            int node = ei[p * N_EDGES + e0 + row];
            *(float4*)&inter_s[row * 256 + c4 * 4] =
                *(const float4*)&out[(size_t)node * HD + c4 * 4];
        }
        __syncthreads();
#pragma unroll 4
        for (int kk = 0; kk < 256; ++kk) {
            float4 w = *(const float4*)&W1[(p * 256 + kk) * 128 + tx * 4];
            float a0 = inter_s[(ty * 4 + 0) * 256 + kk];
            float a1 = inter_s[(ty * 4 + 1) * 256 + kk];
            float a2 = inter_s[(ty * 4 + 2) * 256 + kk];
            float a3 = inter_s[(ty * 4 + 3) * 256 + kk];
            acc[0][0] += a0 * w.x; acc[0][1] += a0 * w.y; acc[0][2] += a0 * w.z; acc[0][3] += a0 * w.w;
            acc[1][0] += a1 * w.x; acc[1][1] += a1 * w.y; acc[1][2] += a1 * w.z; acc[1][3] += a1 * w.w;
            acc[2][0] += a2 * w.x; acc[2][1] += a2 * w.y; acc[2][2] += a2 * w.z; acc[2][3] += a2 * w.w;
            acc[3][0] += a3 * w.x; acc[3][1] += a3 * w.y; acc[3][2] += a3 * w.z; acc[3][3] += a3 * w.w;
        }
        __syncthreads();
    }

    {
        float4 bb = *(const float4*)&b1[tx * 4];
        float bv[4] = {bb.x, bb.y, bb.z, bb.w};
#pragma unroll
        for (int r = 0; r < 4; ++r)
#pragma unroll
            for (int c = 0; c < 4; ++c)
                h1[(ty * 4 + r) * 132 + tx * 4 + c] = fmaxf(acc[r][c] + bv[c], 0.f);
    }
    __syncthreads();

    const int tx2 = t & 15;
    const int ty2 = t >> 4;
    float acc2[2][4] = {{0.f}};
#pragma unroll 8
    for (int kk = 0; kk < 128; ++kk) {
        float4 w = *(const float4*)&W2[kk * 64 + tx2 * 4];
        float a0 = h1[(ty2 * 2 + 0) * 132 + kk];
        float a1 = h1[(ty2 * 2 + 1) * 132 + kk];
        acc2[0][0] += a0 * w.x; acc2[0][1] += a0 * w.y; acc2[0][2] += a0 * w.z; acc2[0][3] += a0 * w.w;
        acc2[1][0] += a1 * w.x; acc2[1][1] += a1 * w.y; acc2[1][2] += a1 * w.z; acc2[1][3] += a1 * w.w;
    }
    {
        float4 bb = *(const float4*)&b2[tx2 * 4];
        float bv[4] = {bb.x, bb.y, bb.z, bb.w};
#pragma unroll
        for (int i = 0; i < 2; ++i)
#pragma unroll
            for (int c = 0; c < 4; ++c)
                h2[(ty2 * 2 + i) * 68 + tx2 * 4 + c] = fmaxf(acc2[i][c] + bv[c], 0.f);
    }
    __syncthreads();

    if (t < 32) {
        float a = b3[0];
#pragma unroll 8
        for (int kk = 0; kk < 64; ++kk)
            a += h2[t * 68 + kk] * W3[kk];
        int e = e0 + t;
        if (e < N_EDGES)
            rating[e] = 4.f / (1.f + __expf(-a)) + 1.f;
    }
}

extern "C" void kernel_launch(void* const* d_in, const int* in_sizes, int n_in,
                              void* d_out, int out_size, void* d_ws, size_t ws_size,
                              hipStream_t stream) {
    const int*   ei  = (const int*)d_in[0];    // [2, E]
    const float* x   = (const float*)d_in[2];
    const float* mem = (const float*)d_in[3];
    const float* Wq  = (const float*)d_in[4];
    const float* bq  = (const float*)d_in[5];
    const float* Wk  = (const float*)d_in[6];
    const float* bk  = (const float*)d_in[7];
    const float* Wv  = (const float*)d_in[8];
    const float* bv  = (const float*)d_in[9];
    const float* Ws  = (const float*)d_in[10];
    const float* bs  = (const float*)d_in[11];
    const float* W1  = (const float*)d_in[12];
    const float* b1  = (const float*)d_in[13];
    const float* W2  = (const float*)d_in[14];
    const float* b2  = (const float*)d_in[15];
    const float* W3  = (const float*)d_in[16];
    const float* b3  = (const float*)d_in[17];
    float* rating = (float*)d_out;

    // Workspace (~218 MB):
    //   A [N,256] f32: q, later v          102.4 MB
    //   B [N,256] f32: k, later skip+agg   102.4 MB
    //   scores [E,4] f32                     6.4 MB
    //   denom  [N,4] f32                     1.6 MB
    //   rp, deg, cursor [N] int              1.2 MB
    //   csr_src [E] int                      1.6 MB
    //   bsum [128] int
    float* ws = (float*)d_ws;
    const size_t NHD = (size_t)N_NODES * HD;
    float* A      = ws;
    float* B      = A + NHD;
    float* scores = B + NHD;
    float* denom  = scores + (size_t)N_EDGES * 4;
    int*   rp      = (int*)(denom + (size_t)N_NODES * 4);
    int*   deg     = rp + N_NODES;
    int*   cursor  = deg + N_NODES;
    int*   csr_src = cursor + N_NODES;
    int*   bsum    = csr_src + N_EDGES;

    const dim3 ggrid((N_NODES + 63) / 64, HD / 64);
    const int nblk  = (N_NODES + 255) / 256;
    const int eblk  = (N_EDGES + 255) / 256;
    const int wgrid = (N_NODES + 3) / 4;

    // CSR build
    init_zero<<<nblk, 256, 0, stream>>>(deg, cursor);
    k_deg<<<eblk, 256, 0, stream>>>(ei, deg);
    k_scan1<<<NB_SCAN, 256, 0, stream>>>(deg, rp, bsum);
    k_scan2<<<1, 256, 0, stream>>>(bsum);
    k_scan3<<<nblk, 256, 0, stream>>>(rp, bsum);
    k_bucket<<<eblk, 256, 0, stream>>>(ei, rp, cursor, csr_src);

    // projections + attention
    node_gemm<<<ggrid, 256, 0, stream>>>(x, mem, Wq, bq, A);   // A = q
    node_gemm<<<ggrid, 256, 0, stream>>>(x, mem, Wk, bk, B);   // B = k
    k_scores_csr<<<wgrid, 256, 0, stream>>>(rp, deg, csr_src, A, B, scores, denom);
    node_gemm<<<ggrid, 256, 0, stream>>>(x, mem, Wv, bv, A);   // A = v
    node_gemm<<<ggrid, 256, 0, stream>>>(x, mem, Ws, bs, B);   // B = skip
    k_agg_csr<<<wgrid, 256, 0, stream>>>(rp, deg, csr_src, scores, denom, A, B);

    // rating MLP
    edge_mlp<<<(N_EDGES + 31) / 32, 256, 0, stream>>>(
        ei, B, W1, b1, W2, b2, W3, b3, rating);
}

// Round 4
// 989.637 us; speedup vs baseline: 3.2910x; 2.0416x over previous
//
#include <hip/hip_runtime.h>
#include <math.h>

#define N_NODES 100000
#define N_EDGES 400000
#define HID 128
#define HEADS 4
#define OUT_C 64
#define HD 256   // HEADS*OUT_C
#define SCAN_CHUNK 1024
#define NB_SCAN ((N_NODES + SCAN_CHUNK - 1) / SCAN_CHUNK)   // 98

typedef __attribute__((ext_vector_type(8))) short bf16x8;   // 8 bf16 = 4 VGPRs
typedef __attribute__((ext_vector_type(4))) float f32x4;

// fp32 -> bf16 round-to-nearest-even
__device__ __forceinline__ unsigned short fbf(float f) {
    unsigned u = __float_as_uint(f);
    unsigned r = (u + 0x7fffu + ((u >> 16) & 1u)) >> 16;
    return (unsigned short)r;
}

// ---------- K0: zero deg + cursor ----------
__global__ __launch_bounds__(256) void init_zero(int* __restrict__ deg,
                                                 int* __restrict__ cursor) {
    int i = blockIdx.x * 256 + threadIdx.x;
    if (i < N_NODES) { deg[i] = 0; cursor[i] = 0; }
}

// ---------- CSR build: degree count ----------
__global__ __launch_bounds__(256) void k_deg(const int* __restrict__ ei,
                                             int* __restrict__ deg) {
    int e = blockIdx.x * 256 + threadIdx.x;
    if (e < N_EDGES) atomicAdd(&deg[ei[N_EDGES + e]], 1);
}

// ---------- scan 1 ----------
__global__ __launch_bounds__(256) void k_scan1(const int* __restrict__ deg,
                                               int* __restrict__ rp,
                                               int* __restrict__ bsum) {
    __shared__ int ts[256];
    int b = blockIdx.x, t = threadIdx.x;
    int base = b * SCAN_CHUNK + t * 4;
    int vv[4];
    int s = 0;
#pragma unroll
    for (int i = 0; i < 4; ++i) {
        int d = (base + i < N_NODES) ? deg[base + i] : 0;
        vv[i] = s;
        s += d;
    }
    ts[t] = s;
    __syncthreads();
    for (int off = 1; off < 256; off <<= 1) {
        int x = (t >= off) ? ts[t - off] : 0;
        __syncthreads();
        ts[t] += x;
        __syncthreads();
    }
    int ex = ts[t] - s;
#pragma unroll
    for (int i = 0; i < 4; ++i)
        if (base + i < N_NODES) rp[base + i] = ex + vv[i];
    if (t == 255) bsum[b] = ts[255];
}

// ---------- scan 2 ----------
__global__ __launch_bounds__(256) void k_scan2(int* __restrict__ bsum) {
    __shared__ int ts[256];
    int t = threadIdx.x;
    int v = (t < NB_SCAN) ? bsum[t] : 0;
    ts[t] = v;
    __syncthreads();
    for (int off = 1; off < 256; off <<= 1) {
        int x = (t >= off) ? ts[t - off] : 0;
        __syncthreads();
        ts[t] += x;
        __syncthreads();
    }
    if (t < NB_SCAN) bsum[t] = ts[t] - v;
}

// ---------- scan 3 ----------
__global__ __launch_bounds__(256) void k_scan3(int* __restrict__ rp,
                                               const int* __restrict__ bsum) {
    int i = blockIdx.x * 256 + threadIdx.x;
    if (i < N_NODES) rp[i] += bsum[i / SCAN_CHUNK];
}

// ---------- bucket ----------
__global__ __launch_bounds__(256) void k_bucket(const int* __restrict__ ei,
                                                const int* __restrict__ rp,
                                                int* __restrict__ cursor,
                                                int* __restrict__ csr_src) {
    int e = blockIdx.x * 256 + threadIdx.x;
    if (e >= N_EDGES) return;
    int src = ei[e];
    int d   = ei[N_EDGES + e];
    int idx = atomicAdd(&cursor[d], 1);
    csr_src[rp[d] + idx] = src;
}

// ---------- pack W1 [512,128] into MFMA B-frag order [kt][nt][lane][8] bf16 ----------
__global__ __launch_bounds__(256) void pack_w1(const float* __restrict__ W1,
                                               unsigned short* __restrict__ W1p) {
    int i = blockIdx.x * 256 + threadIdx.x;   // 16*8*64 = 8192
    if (i >= 8192) return;
    int lane = i & 63, nt = (i >> 6) & 7, kt = i >> 9;
    int q = lane >> 4, c = lane & 15;
#pragma unroll
    for (int j = 0; j < 8; ++j)
        W1p[i * 8 + j] = fbf(W1[(kt * 32 + q * 8 + j) * 128 + nt * 16 + c]);
}

// ---------- pack W2 [128,64] -> [kt][nt][lane][8] bf16 ----------
__global__ __launch_bounds__(256) void pack_w2(const float* __restrict__ W2,
                                               unsigned short* __restrict__ W2p) {
    int i = blockIdx.x * 256 + threadIdx.x;   // 4*4*64 = 1024
    if (i >= 1024) return;
    int lane = i & 63, nt = (i >> 6) & 3, kt = i >> 8;
    int q = lane >> 4, c = lane & 15;
#pragma unroll
    for (int j = 0; j < 8; ++j)
        W2p[i * 8 + j] = fbf(W2[(kt * 32 + q * 8 + j) * 64 + nt * 16 + c]);
}

// ---------- K1: projection GEMM (fp32, unchanged) ----------
__global__ __launch_bounds__(256) void node_gemm(
    const float* __restrict__ x, const float* __restrict__ mem,
    const float* __restrict__ W, const float* __restrict__ bias,
    float* __restrict__ O)
{
    __shared__ float As[64 * 130];
    __shared__ float Bs[64 * 64];

    const int t  = threadIdx.x;
    const int m0 = blockIdx.x * 64;
    const int n0 = blockIdx.y * 64;

    {
        const float4* x4 = (const float4*)x;
        const float4* m4 = (const float4*)mem;
#pragma unroll
        for (int j = 0; j < 8; ++j) {
            int idx = t + j * 256;
            int row = idx >> 5;
            int c4  = idx & 31;
            int gr  = m0 + row;
            float4 val = make_float4(0.f, 0.f, 0.f, 0.f);
            if (gr < N_NODES) {
                float4 a = x4[gr * 32 + c4];
                float4 b = m4[gr * 32 + c4];
                val = make_float4(a.x + b.x, a.y + b.y, a.z + b.z, a.w + b.w);
            }
            float* dst = &As[row * 130 + c4 * 4];
            dst[0] = val.x; dst[1] = val.y; dst[2] = val.z; dst[3] = val.w;
        }
    }

    const int tx = t & 15;
    const int ty = t >> 4;
    float acc[4][4] = {{0.f}};

    for (int kc = 0; kc < 2; ++kc) {
        __syncthreads();
#pragma unroll
        for (int j = 0; j < 4; ++j) {
            int idx = t + j * 256;
            int kk  = idx >> 4;
            int c4  = idx & 15;
            *(float4*)&Bs[kk * 64 + c4 * 4] =
                *(const float4*)&W[(kc * 64 + kk) * HD + n0 + c4 * 4];
        }
        __syncthreads();
#pragma unroll 8
        for (int kk = 0; kk < 64; ++kk) {
            int kg = kc * 64 + kk;
            float a0 = As[(ty * 4 + 0) * 130 + kg];
            float a1 = As[(ty * 4 + 1) * 130 + kg];
            float a2 = As[(ty * 4 + 2) * 130 + kg];
            float a3 = As[(ty * 4 + 3) * 130 + kg];
            float4 b = *(const float4*)&Bs[kk * 64 + tx * 4];
            acc[0][0] += a0 * b.x; acc[0][1] += a0 * b.y; acc[0][2] += a0 * b.z; acc[0][3] += a0 * b.w;
            acc[1][0] += a1 * b.x; acc[1][1] += a1 * b.y; acc[1][2] += a1 * b.z; acc[1][3] += a1 * b.w;
            acc[2][0] += a2 * b.x; acc[2][1] += a2 * b.y; acc[2][2] += a2 * b.z; acc[2][3] += a2 * b.w;
            acc[3][0] += a3 * b.x; acc[3][1] += a3 * b.y; acc[3][2] += a3 * b.z; acc[3][3] += a3 * b.w;
        }
    }

    float4 bb = *(const float4*)&bias[n0 + tx * 4];
#pragma unroll
    for (int r = 0; r < 4; ++r) {
        int gr = m0 + ty * 4 + r;
        if (gr < N_NODES) {
            float4 val = make_float4(acc[r][0] + bb.x, acc[r][1] + bb.y,
                                     acc[r][2] + bb.z, acc[r][3] + bb.w);
            *(float4*)&O[(size_t)gr * HD + n0 + tx * 4] = val;
        }
    }
}

// ---------- K2: per-dst-node scores via CSR ----------
__global__ __launch_bounds__(256) void k_scores_csr(
    const int* __restrict__ rp, const int* __restrict__ deg,
    const int* __restrict__ csr_src,
    const float* __restrict__ q, const float* __restrict__ k,
    float* __restrict__ scores, float* __restrict__ denomArr)
{
    int node = blockIdx.x * 4 + (threadIdx.x >> 6);
    int l = threadIdx.x & 63;
    if (node >= N_NODES) return;
    int h     = l >> 4;
    int start = rp[node];
    int cnt   = deg[node];

    float4 qq = *(const float4*)&q[(size_t)node * HD + l * 4];

    float m = -1e30f;
    for (int i = 0; i < cnt; ++i) {
        int slot = start + i;
        int src  = csr_src[slot];
        float4 kk = *(const float4*)&k[(size_t)src * HD + l * 4];
        float s = qq.x * kk.x + qq.y * kk.y + qq.z * kk.z + qq.w * kk.w;
        s += __shfl_xor(s, 1);
        s += __shfl_xor(s, 2);
        s += __shfl_xor(s, 4);
        s += __shfl_xor(s, 8);
        s *= 0.125f;                    // 1/sqrt(64)
        if ((l & 15) == 0) scores[slot * 4 + h] = s;
        m = fmaxf(m, s);
    }
    float denom = 0.f;
    for (int i = 0; i < cnt; ++i) {
        int slot = start + i;
        float s  = scores[slot * 4 + h];
        float ev = __expf(s - m);
        if ((l & 15) == 0) scores[slot * 4 + h] = ev;
        denom += ev;
    }
    if ((l & 15) == 0) denomArr[node * 4 + h] = denom;
}

// ---------- K3: per-dst-node aggregation; epilogue converts row to bf16 IN PLACE ----------
// bf16 row occupies the first 512 B of the node's fp32 row (stride stays 1024 B).
// Safe: each row is touched by exactly one wave; its loads complete before stores issue.
__global__ __launch_bounds__(256) void k_agg_csr(
    const int* __restrict__ rp, const int* __restrict__ deg,
    const int* __restrict__ csr_src,
    const float* __restrict__ scores, const float* __restrict__ denomArr,
    const float* __restrict__ v, float* __restrict__ out)
{
    int node = blockIdx.x * 4 + (threadIdx.x >> 6);
    int l = threadIdx.x & 63;
    if (node >= N_NODES) return;
    int h     = l >> 4;
    int start = rp[node];
    int cnt   = deg[node];

    float* op = &out[(size_t)node * HD + l * 4];
    float4 sk = *(const float4*)op;          // skip (loaded before any store)

    float4 acc = make_float4(0.f, 0.f, 0.f, 0.f);
    for (int i = 0; i < cnt; ++i) {
        int slot = start + i;
        int src  = csr_src[slot];
        float e  = scores[slot * 4 + h];
        float4 vv = *(const float4*)&v[(size_t)src * HD + l * 4];
        acc.x += e * vv.x; acc.y += e * vv.y; acc.z += e * vv.z; acc.w += e * vv.w;
    }
    float inv = 1.f / (denomArr[node * 4 + h] + 1e-16f);
    float4 res = make_float4(sk.x + acc.x * inv, sk.y + acc.y * inv,
                             sk.z + acc.z * inv, sk.w + acc.w * inv);
    unsigned short* ob = (unsigned short*)&out[(size_t)node * HD];
    ushort4 bf = make_ushort4(fbf(res.x), fbf(res.y), fbf(res.z), fbf(res.w));
    *(ushort4*)&ob[l * 4] = bf;
}

// ---------- K5: MFMA rating MLP, 64 edges/block, 4 waves ----------
// layer1: [64,512]@[512,128] bf16 MFMA (2 phases of K=256: src cols, dst cols)
// layer2: [64,128]@[128,64]  bf16 MFMA
// layer3: [64,64]@[64,1]     fp32 VALU
__global__ __launch_bounds__(256) void edge_mlp_mfma(
    const int* __restrict__ ei, const unsigned short* __restrict__ outb,
    const unsigned short* __restrict__ W1p, const float* __restrict__ b1,
    const unsigned short* __restrict__ W2p, const float* __restrict__ b2,
    const float* __restrict__ W3, const float* __restrict__ b3,
    float* __restrict__ rating)
{
    __shared__ __align__(16) char lds_raw[64 * 264 * 2];   // inter bf16 [64][264]; later h2 f32 [64][65]
    __shared__ __align__(16) short h1_s[64 * 136];         // h1 bf16 [64][136]
    short* inter_s = (short*)lds_raw;
    float* h2_s    = (float*)lds_raw;

    const int t = threadIdx.x;
    const int w = t >> 6, l = t & 63;
    const int q = l >> 4, c = l & 15;
    const int e0 = blockIdx.x * 64;

    f32x4 acc[8];
#pragma unroll
    for (int i = 0; i < 8; ++i) acc[i] = (f32x4){0.f, 0.f, 0.f, 0.f};

    for (int p = 0; p < 2; ++p) {
        // gather 64 rows of outb (bf16, 512 B each): p=0 src half, p=1 dst half
#pragma unroll
        for (int j = 0; j < 8; ++j) {
            int idx = t + j * 256;           // 2048 chunks of 16 B
            int row = idx >> 5, c4 = idx & 31;
            int node = ei[p * N_EDGES + e0 + row];
            *(bf16x8*)&inter_s[row * 264 + c4 * 8] =
                *(const bf16x8*)&outb[(size_t)node * 512 + c4 * 8];
        }
        __syncthreads();
#pragma unroll
        for (int kt = 0; kt < 8; ++kt) {
            bf16x8 av = *(const bf16x8*)&inter_s[(w * 16 + c) * 264 + kt * 32 + q * 8];
#pragma unroll
            for (int nt = 0; nt < 8; ++nt) {
                bf16x8 bv = *(const bf16x8*)&W1p[(size_t)(((p * 8 + kt) * 8 + nt) * 64 + l) * 8];
                acc[nt] = __builtin_amdgcn_mfma_f32_16x16x32_bf16(av, bv, acc[nt], 0, 0, 0);
            }
        }
        __syncthreads();
    }

    // epilogue layer1: bias + relu -> h1 bf16.  D: row=(q*4+r) in wave tile, col=nt*16+c
#pragma unroll
    for (int nt = 0; nt < 8; ++nt) {
        float bv = b1[nt * 16 + c];
#pragma unroll
        for (int r = 0; r < 4; ++r)
            h1_s[(w * 16 + q * 4 + r) * 136 + nt * 16 + c] =
                (short)fbf(fmaxf(acc[nt][r] + bv, 0.f));
    }
    __syncthreads();

    // layer2 MFMA
    f32x4 acc2[4];
#pragma unroll
    for (int i = 0; i < 4; ++i) acc2[i] = (f32x4){0.f, 0.f, 0.f, 0.f};
#pragma unroll
    for (int kt = 0; kt < 4; ++kt) {
        bf16x8 av = *(const bf16x8*)&h1_s[(w * 16 + c) * 136 + kt * 32 + q * 8];
#pragma unroll
        for (int nt = 0; nt < 4; ++nt) {
            bf16x8 bv = *(const bf16x8*)&W2p[(size_t)((kt * 4 + nt) * 64 + l) * 8];
            acc2[nt] = __builtin_amdgcn_mfma_f32_16x16x32_bf16(av, bv, acc2[nt], 0, 0, 0);
        }
    }
    __syncthreads();   // everyone done with inter_s reads long ago; h2 aliases lds_raw

    // epilogue layer2: bias + relu -> h2 f32 [64][65]
#pragma unroll
    for (int nt = 0; nt < 4; ++nt) {
        float bv = b2[nt * 16 + c];
#pragma unroll
        for (int r = 0; r < 4; ++r)
            h2_s[(w * 16 + q * 4 + r) * 65 + nt * 16 + c] = fmaxf(acc2[nt][r] + bv, 0.f);
    }
    __syncthreads();

    // layer3: one thread per edge (wave 0)
    if (t < 64) {
        float a = b3[0];
#pragma unroll 8
        for (int kk = 0; kk < 64; ++kk)
            a += h2_s[t * 65 + kk] * W3[kk];
        rating[e0 + t] = 4.f / (1.f + __expf(-a)) + 1.f;
    }
}

extern "C" void kernel_launch(void* const* d_in, const int* in_sizes, int n_in,
                              void* d_out, int out_size, void* d_ws, size_t ws_size,
                              hipStream_t stream) {
    const int*   ei  = (const int*)d_in[0];    // [2, E]
    const float* x   = (const float*)d_in[2];
    const float* mem = (const float*)d_in[3];
    const float* Wq  = (const float*)d_in[4];
    const float* bq  = (const float*)d_in[5];
    const float* Wk  = (const float*)d_in[6];
    const float* bk  = (const float*)d_in[7];
    const float* Wv  = (const float*)d_in[8];
    const float* bv  = (const float*)d_in[9];
    const float* Ws  = (const float*)d_in[10];
    const float* bs  = (const float*)d_in[11];
    const float* W1  = (const float*)d_in[12];
    const float* b1  = (const float*)d_in[13];
    const float* W2  = (const float*)d_in[14];
    const float* b2  = (const float*)d_in[15];
    const float* W3  = (const float*)d_in[16];
    const float* b3  = (const float*)d_in[17];
    float* rating = (float*)d_out;

    // Workspace (~215 MB, same proven-safe envelope as R2):
    //   A [N,256] f32: q, later v            102.4 MB
    //   B [N,256] f32: k, later skip+out     102.4 MB  (bf16 out packed in-place)
    //   scores [E,4] f32                       6.4 MB
    //   denom  [N,4] f32                       1.6 MB
    //   rp, deg, cursor [N] int                1.2 MB
    //   csr_src [E] int                        1.6 MB
    //   bsum [128] int; W1p 128 KB; W2p 16 KB
    float* ws = (float*)d_ws;
    const size_t NHD = (size_t)N_NODES * HD;
    float* A      = ws;
    float* B      = A + NHD;
    float* scores = B + NHD;
    float* denom  = scores + (size_t)N_EDGES * 4;
    int*   rp      = (int*)(denom + (size_t)N_NODES * 4);
    int*   deg     = rp + N_NODES;
    int*   cursor  = deg + N_NODES;
    int*   csr_src = cursor + N_NODES;
    int*   bsum    = csr_src + N_EDGES;
    unsigned short* W1p = (unsigned short*)(bsum + 128);
    unsigned short* W2p = W1p + 8192 * 8;

    const dim3 ggrid((N_NODES + 63) / 64, HD / 64);
    const int nblk  = (N_NODES + 255) / 256;
    const int eblk  = (N_EDGES + 255) / 256;
    const int wgrid = (N_NODES + 3) / 4;

    // CSR build + weight packing
    init_zero<<<nblk, 256, 0, stream>>>(deg, cursor);
    k_deg<<<eblk, 256, 0, stream>>>(ei, deg);
    k_scan1<<<NB_SCAN, 256, 0, stream>>>(deg, rp, bsum);
    k_scan2<<<1, 256, 0, stream>>>(bsum);
    k_scan3<<<nblk, 256, 0, stream>>>(rp, bsum);
    k_bucket<<<eblk, 256, 0, stream>>>(ei, rp, cursor, csr_src);
    pack_w1<<<32, 256, 0, stream>>>(W1, W1p);
    pack_w2<<<4, 256, 0, stream>>>(W2, W2p);

    // projections + attention
    node_gemm<<<ggrid, 256, 0, stream>>>(x, mem, Wq, bq, A);   // A = q
    node_gemm<<<ggrid, 256, 0, stream>>>(x, mem, Wk, bk, B);   // B = k
    k_scores_csr<<<wgrid, 256, 0, stream>>>(rp, deg, csr_src, A, B, scores, denom);
    node_gemm<<<ggrid, 256, 0, stream>>>(x, mem, Wv, bv, A);   // A = v
    node_gemm<<<ggrid, 256, 0, stream>>>(x, mem, Ws, bs, B);   // B = skip
    k_agg_csr<<<wgrid, 256, 0, stream>>>(rp, deg, csr_src, scores, denom, A, B);

    // rating MLP (MFMA) — reads bf16 rows packed in B
    edge_mlp_mfma<<<N_EDGES / 64, 256, 0, stream>>>(
        ei, (const unsigned short*)B, W1p, b1, W2p, b2, W3, b3, rating);
}

// Round 5
// 757.006 us; speedup vs baseline: 4.3023x; 1.3073x over previous
//
#include <hip/hip_runtime.h>
#include <math.h>

#define N_NODES 100000
#define N_EDGES 400000
#define HID 128
#define HEADS 4
#define OUT_C 64
#define HD 256   // HEADS*OUT_C
#define SCAN_CHUNK 1024
#define NB_SCAN ((N_NODES + SCAN_CHUNK - 1) / SCAN_CHUNK)   // 98

typedef __attribute__((ext_vector_type(8))) short bf16x8;   // 8 bf16 = 4 VGPRs
typedef __attribute__((ext_vector_type(4))) float f32x4;

// fp32 -> bf16 round-to-nearest-even
__device__ __forceinline__ unsigned short fbf(float f) {
    unsigned u = __float_as_uint(f);
    unsigned r = (u + 0x7fffu + ((u >> 16) & 1u)) >> 16;
    return (unsigned short)r;
}
__device__ __forceinline__ float bf2f(unsigned short u) {
    return __uint_as_float(((unsigned)u) << 16);
}

// ---------- K0: zero deg + cursor ----------
__global__ __launch_bounds__(256) void init_zero(int* __restrict__ deg,
                                                 int* __restrict__ cursor) {
    int i = blockIdx.x * 256 + threadIdx.x;
    if (i < N_NODES) { deg[i] = 0; cursor[i] = 0; }
}

// ---------- CSR build: degree count ----------
__global__ __launch_bounds__(256) void k_deg(const int* __restrict__ ei,
                                             int* __restrict__ deg) {
    int e = blockIdx.x * 256 + threadIdx.x;
    if (e < N_EDGES) atomicAdd(&deg[ei[N_EDGES + e]], 1);
}

// ---------- scan 1 ----------
__global__ __launch_bounds__(256) void k_scan1(const int* __restrict__ deg,
                                               int* __restrict__ rp,
                                               int* __restrict__ bsum) {
    __shared__ int ts[256];
    int b = blockIdx.x, t = threadIdx.x;
    int base = b * SCAN_CHUNK + t * 4;
    int vv[4];
    int s = 0;
#pragma unroll
    for (int i = 0; i < 4; ++i) {
        int d = (base + i < N_NODES) ? deg[base + i] : 0;
        vv[i] = s;
        s += d;
    }
    ts[t] = s;
    __syncthreads();
    for (int off = 1; off < 256; off <<= 1) {
        int x = (t >= off) ? ts[t - off] : 0;
        __syncthreads();
        ts[t] += x;
        __syncthreads();
    }
    int ex = ts[t] - s;
#pragma unroll
    for (int i = 0; i < 4; ++i)
        if (base + i < N_NODES) rp[base + i] = ex + vv[i];
    if (t == 255) bsum[b] = ts[255];
}

// ---------- scan 2 ----------
__global__ __launch_bounds__(256) void k_scan2(int* __restrict__ bsum) {
    __shared__ int ts[256];
    int t = threadIdx.x;
    int v = (t < NB_SCAN) ? bsum[t] : 0;
    ts[t] = v;
    __syncthreads();
    for (int off = 1; off < 256; off <<= 1) {
        int x = (t >= off) ? ts[t - off] : 0;
        __syncthreads();
        ts[t] += x;
        __syncthreads();
    }
    if (t < NB_SCAN) bsum[t] = ts[t] - v;
}

// ---------- scan 3 ----------
__global__ __launch_bounds__(256) void k_scan3(int* __restrict__ rp,
                                               const int* __restrict__ bsum) {
    int i = blockIdx.x * 256 + threadIdx.x;
    if (i < N_NODES) rp[i] += bsum[i / SCAN_CHUNK];
}

// ---------- bucket ----------
__global__ __launch_bounds__(256) void k_bucket(const int* __restrict__ ei,
                                                const int* __restrict__ rp,
                                                int* __restrict__ cursor,
                                                int* __restrict__ csr_src) {
    int e = blockIdx.x * 256 + threadIdx.x;
    if (e >= N_EDGES) return;
    int src = ei[e];
    int d   = ei[N_EDGES + e];
    int idx = atomicAdd(&cursor[d], 1);
    csr_src[rp[d] + idx] = src;
}

// ---------- pack 4 projection weights [128,256] -> [z][kt][nt][lane][8] bf16 ----------
__global__ __launch_bounds__(256) void pack_wg(
    const float* __restrict__ Wq, const float* __restrict__ Wk,
    const float* __restrict__ Wv, const float* __restrict__ Ws,
    unsigned short* __restrict__ Wp) {
    int i = blockIdx.x * 256 + threadIdx.x;   // 4*4*16*64 = 16384
    if (i >= 16384) return;
    int lane = i & 63, nt = (i >> 6) & 15, kt = (i >> 10) & 3, z = i >> 12;
    const float* W = (z == 0) ? Wq : (z == 1) ? Wk : (z == 2) ? Wv : Ws;
    int q = lane >> 4, c = lane & 15;
#pragma unroll
    for (int j = 0; j < 8; ++j)
        Wp[i * 8 + j] = fbf(W[(kt * 32 + q * 8 + j) * HD + nt * 16 + c]);
}

// ---------- pack W1 [512,128] into MFMA B-frag order [kt][nt][lane][8] bf16 ----------
__global__ __launch_bounds__(256) void pack_w1(const float* __restrict__ W1,
                                               unsigned short* __restrict__ W1p) {
    int i = blockIdx.x * 256 + threadIdx.x;   // 16*8*64 = 8192
    if (i >= 8192) return;
    int lane = i & 63, nt = (i >> 6) & 7, kt = i >> 9;
    int q = lane >> 4, c = lane & 15;
#pragma unroll
    for (int j = 0; j < 8; ++j)
        W1p[i * 8 + j] = fbf(W1[(kt * 32 + q * 8 + j) * 128 + nt * 16 + c]);
}

// ---------- pack W2 [128,64] -> [kt][nt][lane][8] bf16 ----------
__global__ __launch_bounds__(256) void pack_w2(const float* __restrict__ W2,
                                               unsigned short* __restrict__ W2p) {
    int i = blockIdx.x * 256 + threadIdx.x;   // 4*4*64 = 1024
    if (i >= 1024) return;
    int lane = i & 63, nt = (i >> 6) & 3, kt = i >> 8;
    int q = lane >> 4, c = lane & 15;
#pragma unroll
    for (int j = 0; j < 8; ++j)
        W2p[i * 8 + j] = fbf(W2[(kt * 32 + q * 8 + j) * 64 + nt * 16 + c]);
}

// ---------- K1: fused projection GEMM (MFMA bf16) ----------
// All four projections in one kernel: A = bf16(x+mem) [64 rows], W from packed
// frags, K=128 single-shot, outputs bf16 [N,256] per z. Wave w owns cols
// [w*64, w*64+64); per wave per z: 4 mt x 4 nt accum tiles, 4 kt steps.
__global__ __launch_bounds__(256) void gemm_proj(
    const float* __restrict__ x, const float* __restrict__ mem,
    const unsigned short* __restrict__ Wp,
    const float* __restrict__ bq, const float* __restrict__ bk,
    const float* __restrict__ bv, const float* __restrict__ bs,
    unsigned short* __restrict__ Q, unsigned short* __restrict__ K,
    unsigned short* __restrict__ V, unsigned short* __restrict__ S)
{
    __shared__ __align__(16) short As[64 * 136];   // bf16(x+mem), row pad 136

    const int t = threadIdx.x;
    const int w = t >> 6, l = t & 63;
    const int q = l >> 4, c = l & 15;
    const int m0 = blockIdx.x * 64;

    // stage A = bf16(x+mem)[m0..m0+64, 0..128)
    {
        const float4* x4 = (const float4*)x;
        const float4* m4 = (const float4*)mem;
#pragma unroll
        for (int j = 0; j < 8; ++j) {
            int idx = t + j * 256;       // 2048 float4 chunks
            int row = idx >> 5, c4 = idx & 31;
            int gr  = m0 + row;
            ushort4 hv = make_ushort4(0, 0, 0, 0);
            if (gr < N_NODES) {
                float4 a = x4[(size_t)gr * 32 + c4];
                float4 b = m4[(size_t)gr * 32 + c4];
                hv = make_ushort4(fbf(a.x + b.x), fbf(a.y + b.y),
                                  fbf(a.z + b.z), fbf(a.w + b.w));
            }
            *(ushort4*)&As[row * 136 + c4 * 4] = hv;
        }
    }
    __syncthreads();

    for (int z = 0; z < 4; ++z) {
        const float* bz = (z == 0) ? bq : (z == 1) ? bk : (z == 2) ? bv : bs;
        unsigned short* Oz = (z == 0) ? Q : (z == 1) ? K : (z == 2) ? V : S;

        f32x4 acc[4][4];
#pragma unroll
        for (int mt = 0; mt < 4; ++mt)
#pragma unroll
            for (int nt = 0; nt < 4; ++nt) acc[mt][nt] = (f32x4){0.f, 0.f, 0.f, 0.f};

#pragma unroll
        for (int kt = 0; kt < 4; ++kt) {
            bf16x8 af[4];
#pragma unroll
            for (int mt = 0; mt < 4; ++mt)
                af[mt] = *(const bf16x8*)&As[(mt * 16 + c) * 136 + kt * 32 + q * 8];
#pragma unroll
            for (int nt = 0; nt < 4; ++nt) {
                int ntg = w * 4 + nt;
                bf16x8 bv8 = *(const bf16x8*)&Wp[(size_t)(((z * 4 + kt) * 16 + ntg) * 64 + l) * 8];
#pragma unroll
                for (int mt = 0; mt < 4; ++mt)
                    acc[mt][nt] = __builtin_amdgcn_mfma_f32_16x16x32_bf16(af[mt], bv8, acc[mt][nt], 0, 0, 0);
            }
        }

        // epilogue: bias + bf16 store.  C: row = q*4+r (in 16-tile), col = c
#pragma unroll
        for (int nt = 0; nt < 4; ++nt) {
            int col = w * 64 + nt * 16 + c;
            float bb = bz[col];
#pragma unroll
            for (int mt = 0; mt < 4; ++mt) {
#pragma unroll
                for (int r = 0; r < 4; ++r) {
                    int row = m0 + mt * 16 + q * 4 + r;
                    if (row < N_NODES)
                        Oz[(size_t)row * HD + col] = fbf(acc[mt][nt][r] + bb);
                }
            }
        }
    }
}

// ---------- K2: fused attention, online softmax, one wave per node ----------
// lane l: dims 4l..4l+3 ; head = l>>4. Writes out (bf16) in-place over Q.
__global__ __launch_bounds__(256) void k_attn(
    const int* __restrict__ rp, const int* __restrict__ deg,
    const int* __restrict__ csr_src,
    const unsigned short* __restrict__ Q, const unsigned short* __restrict__ K,
    const unsigned short* __restrict__ V, const unsigned short* __restrict__ S,
    unsigned short* __restrict__ out)
{
    int node = blockIdx.x * 4 + (threadIdx.x >> 6);
    int l = threadIdx.x & 63;
    if (node >= N_NODES) return;
    int start = rp[node];
    int cnt   = deg[node];

    float q0, q1, q2, q3;
    {
        ushort4 u = *(const ushort4*)&Q[(size_t)node * HD + l * 4];
        q0 = bf2f(u.x); q1 = bf2f(u.y); q2 = bf2f(u.z); q3 = bf2f(u.w);
    }

    float m = -1e30f, d = 0.f;
    float a0 = 0.f, a1 = 0.f, a2 = 0.f, a3 = 0.f;

    for (int i = 0; i < cnt; ++i) {
        int src = csr_src[start + i];
        ushort4 ku = *(const ushort4*)&K[(size_t)src * HD + l * 4];
        float s = q0 * bf2f(ku.x) + q1 * bf2f(ku.y) + q2 * bf2f(ku.z) + q3 * bf2f(ku.w);
        s += __shfl_xor(s, 1);
        s += __shfl_xor(s, 2);
        s += __shfl_xor(s, 4);
        s += __shfl_xor(s, 8);
        s *= 0.125f;                       // 1/sqrt(64)

        float mn    = fmaxf(m, s);
        float scale = __expf(m - mn);      // first iter: exp(-huge)=0
        float e     = __expf(s - mn);
        d = d * scale + e;
        ushort4 vu = *(const ushort4*)&V[(size_t)src * HD + l * 4];
        a0 = a0 * scale + e * bf2f(vu.x);
        a1 = a1 * scale + e * bf2f(vu.y);
        a2 = a2 * scale + e * bf2f(vu.z);
        a3 = a3 * scale + e * bf2f(vu.w);
        m = mn;
    }

    float inv = 1.f / (d + 1e-16f);
    ushort4 su = *(const ushort4*)&S[(size_t)node * HD + l * 4];
    ushort4 ov = make_ushort4(fbf(bf2f(su.x) + a0 * inv),
                              fbf(bf2f(su.y) + a1 * inv),
                              fbf(bf2f(su.z) + a2 * inv),
                              fbf(bf2f(su.w) + a3 * inv));
    *(ushort4*)&out[(size_t)node * HD + l * 4] = ov;
}

// ---------- K5: MFMA rating MLP, 64 edges/block (dense bf16 out table) ----------
__global__ __launch_bounds__(256) void edge_mlp_mfma(
    const int* __restrict__ ei, const unsigned short* __restrict__ outb,
    const unsigned short* __restrict__ W1p, const float* __restrict__ b1,
    const unsigned short* __restrict__ W2p, const float* __restrict__ b2,
    const float* __restrict__ W3, const float* __restrict__ b3,
    float* __restrict__ rating)
{
    __shared__ __align__(16) char lds_raw[64 * 264 * 2];   // inter bf16 [64][264]; later h2 f32 [64][65]
    __shared__ __align__(16) short h1_s[64 * 136];
    short* inter_s = (short*)lds_raw;
    float* h2_s    = (float*)lds_raw;

    const int t = threadIdx.x;
    const int w = t >> 6, l = t & 63;
    const int q = l >> 4, c = l & 15;
    const int e0 = blockIdx.x * 64;

    f32x4 acc[8];
#pragma unroll
    for (int i = 0; i < 8; ++i) acc[i] = (f32x4){0.f, 0.f, 0.f, 0.f};

    for (int p = 0; p < 2; ++p) {
#pragma unroll
        for (int j = 0; j < 8; ++j) {
            int idx = t + j * 256;           // 2048 chunks of 16 B
            int row = idx >> 5, c4 = idx & 31;
            int node = ei[p * N_EDGES + e0 + row];
            *(bf16x8*)&inter_s[row * 264 + c4 * 8] =
                *(const bf16x8*)&outb[(size_t)node * HD + c4 * 8];
        }
        __syncthreads();
#pragma unroll
        for (int kt = 0; kt < 8; ++kt) {
            bf16x8 av = *(const bf16x8*)&inter_s[(w * 16 + c) * 264 + kt * 32 + q * 8];
#pragma unroll
            for (int nt = 0; nt < 8; ++nt) {
                bf16x8 bv = *(const bf16x8*)&W1p[(size_t)(((p * 8 + kt) * 8 + nt) * 64 + l) * 8];
                acc[nt] = __builtin_amdgcn_mfma_f32_16x16x32_bf16(av, bv, acc[nt], 0, 0, 0);
            }
        }
        __syncthreads();
    }

#pragma unroll
    for (int nt = 0; nt < 8; ++nt) {
        float bv = b1[nt * 16 + c];
#pragma unroll
        for (int r = 0; r < 4; ++r)
            h1_s[(w * 16 + q * 4 + r) * 136 + nt * 16 + c] =
                (short)fbf(fmaxf(acc[nt][r] + bv, 0.f));
    }
    __syncthreads();

    f32x4 acc2[4];
#pragma unroll
    for (int i = 0; i < 4; ++i) acc2[i] = (f32x4){0.f, 0.f, 0.f, 0.f};
#pragma unroll
    for (int kt = 0; kt < 4; ++kt) {
        bf16x8 av = *(const bf16x8*)&h1_s[(w * 16 + c) * 136 + kt * 32 + q * 8];
#pragma unroll
        for (int nt = 0; nt < 4; ++nt) {
            bf16x8 bv = *(const bf16x8*)&W2p[(size_t)((kt * 4 + nt) * 64 + l) * 8];
            acc2[nt] = __builtin_amdgcn_mfma_f32_16x16x32_bf16(av, bv, acc2[nt], 0, 0, 0);
        }
    }
    __syncthreads();

#pragma unroll
    for (int nt = 0; nt < 4; ++nt) {
        float bv = b2[nt * 16 + c];
#pragma unroll
        for (int r = 0; r < 4; ++r)
            h2_s[(w * 16 + q * 4 + r) * 65 + nt * 16 + c] = fmaxf(acc2[nt][r] + bv, 0.f);
    }
    __syncthreads();

    if (t < 64) {
        float a = b3[0];
#pragma unroll 8
        for (int kk = 0; kk < 64; ++kk)
            a += h2_s[t * 65 + kk] * W3[kk];
        rating[e0 + t] = 4.f / (1.f + __expf(-a)) + 1.f;
    }
}

extern "C" void kernel_launch(void* const* d_in, const int* in_sizes, int n_in,
                              void* d_out, int out_size, void* d_ws, size_t ws_size,
                              hipStream_t stream) {
    const int*   ei  = (const int*)d_in[0];    // [2, E]
    const float* x   = (const float*)d_in[2];
    const float* mem = (const float*)d_in[3];
    const float* Wq  = (const float*)d_in[4];
    const float* bq  = (const float*)d_in[5];
    const float* Wk  = (const float*)d_in[6];
    const float* bk  = (const float*)d_in[7];
    const float* Wv  = (const float*)d_in[8];
    const float* bv  = (const float*)d_in[9];
    const float* Ws  = (const float*)d_in[10];
    const float* bs  = (const float*)d_in[11];
    const float* W1  = (const float*)d_in[12];
    const float* b1  = (const float*)d_in[13];
    const float* W2  = (const float*)d_in[14];
    const float* b2  = (const float*)d_in[15];
    const float* W3  = (const float*)d_in[16];
    const float* b3  = (const float*)d_in[17];
    float* rating = (float*)d_out;

    // Workspace (~208 MB, under proven-safe 214 MB):
    //   Q [N,256] bf16 (becomes `out` in-place)   51.2 MB
    //   K,V,S [N,256] bf16                       153.6 MB
    //   rp, deg, cursor [N] int                    1.2 MB
    //   csr_src [E] int                            1.6 MB
    //   bsum[128]; Wp 256 KB; W1p 128 KB; W2p 16 KB
    unsigned short* Q = (unsigned short*)d_ws;
    const size_t NHDe = (size_t)N_NODES * HD;   // 25.6M elements
    unsigned short* K = Q + NHDe;
    unsigned short* V = K + NHDe;
    unsigned short* S = V + NHDe;
    int* rp      = (int*)(S + NHDe);
    int* deg     = rp + N_NODES;
    int* cursor  = deg + N_NODES;
    int* csr_src = cursor + N_NODES;
    int* bsum    = csr_src + N_EDGES;
    unsigned short* Wp  = (unsigned short*)(bsum + 128);
    unsigned short* W1p = Wp + 16384 * 8;
    unsigned short* W2p = W1p + 8192 * 8;

    const int nblk  = (N_NODES + 255) / 256;
    const int eblk  = (N_EDGES + 255) / 256;
    const int wgrid = (N_NODES + 3) / 4;

    // CSR build + weight packing
    init_zero<<<nblk, 256, 0, stream>>>(deg, cursor);
    k_deg<<<eblk, 256, 0, stream>>>(ei, deg);
    k_scan1<<<NB_SCAN, 256, 0, stream>>>(deg, rp, bsum);
    k_scan2<<<1, 256, 0, stream>>>(bsum);
    k_scan3<<<nblk, 256, 0, stream>>>(rp, bsum);
    k_bucket<<<eblk, 256, 0, stream>>>(ei, rp, cursor, csr_src);
    pack_wg<<<64, 256, 0, stream>>>(Wq, Wk, Wv, Ws, Wp);
    pack_w1<<<32, 256, 0, stream>>>(W1, W1p);
    pack_w2<<<4, 256, 0, stream>>>(W2, W2p);

    // fused projections (q/k/v/skip) -> bf16 tables
    gemm_proj<<<(N_NODES + 63) / 64, 256, 0, stream>>>(
        x, mem, Wp, bq, bk, bv, bs, Q, K, V, S);

    // fused online-softmax attention; out (bf16) overwrites Q
    k_attn<<<wgrid, 256, 0, stream>>>(rp, deg, csr_src, Q, K, V, S, Q);

    // rating MLP (MFMA) on dense bf16 out table
    edge_mlp_mfma<<<N_EDGES / 64, 256, 0, stream>>>(
        ei, Q, W1p, b1, W2p, b2, W3, b3, rating);
}

// Round 6
// 566.989 us; speedup vs baseline: 5.7441x; 1.3351x over previous
//
#include <hip/hip_runtime.h>
#include <math.h>

#define N_NODES 100000
#define N_EDGES 400000
#define HID 128
#define HEADS 4
#define OUT_C 64
#define HD 256   // HEADS*OUT_C
#define SCAN_CHUNK 1024
#define NB_SCAN ((N_NODES + SCAN_CHUNK - 1) / SCAN_CHUNK)   // 98

typedef __attribute__((ext_vector_type(8))) short bf16x8;   // 8 bf16 = 4 VGPRs
typedef __attribute__((ext_vector_type(4))) float f32x4;

// fp32 -> bf16 round-to-nearest-even
__device__ __forceinline__ unsigned short fbf(float f) {
    unsigned u = __float_as_uint(f);
    unsigned r = (u + 0x7fffu + ((u >> 16) & 1u)) >> 16;
    return (unsigned short)r;
}
__device__ __forceinline__ float bf2f(unsigned short u) {
    return __uint_as_float(((unsigned)u) << 16);
}

// ---------- K0: zero deg + cursor ----------
__global__ __launch_bounds__(256) void init_zero(int* __restrict__ deg,
                                                 int* __restrict__ cursor) {
    int i = blockIdx.x * 256 + threadIdx.x;
    if (i < N_NODES) { deg[i] = 0; cursor[i] = 0; }
}

// ---------- CSR build: degree count ----------
__global__ __launch_bounds__(256) void k_deg(const int* __restrict__ ei,
                                             int* __restrict__ deg) {
    int e = blockIdx.x * 256 + threadIdx.x;
    if (e < N_EDGES) atomicAdd(&deg[ei[N_EDGES + e]], 1);
}

// ---------- scan 1 ----------
__global__ __launch_bounds__(256) void k_scan1(const int* __restrict__ deg,
                                               int* __restrict__ rp,
                                               int* __restrict__ bsum) {
    __shared__ int ts[256];
    int b = blockIdx.x, t = threadIdx.x;
    int base = b * SCAN_CHUNK + t * 4;
    int vv[4];
    int s = 0;
#pragma unroll
    for (int i = 0; i < 4; ++i) {
        int d = (base + i < N_NODES) ? deg[base + i] : 0;
        vv[i] = s;
        s += d;
    }
    ts[t] = s;
    __syncthreads();
    for (int off = 1; off < 256; off <<= 1) {
        int x = (t >= off) ? ts[t - off] : 0;
        __syncthreads();
        ts[t] += x;
        __syncthreads();
    }
    int ex = ts[t] - s;
#pragma unroll
    for (int i = 0; i < 4; ++i)
        if (base + i < N_NODES) rp[base + i] = ex + vv[i];
    if (t == 255) bsum[b] = ts[255];
}

// ---------- scan 2 ----------
__global__ __launch_bounds__(256) void k_scan2(int* __restrict__ bsum) {
    __shared__ int ts[256];
    int t = threadIdx.x;
    int v = (t < NB_SCAN) ? bsum[t] : 0;
    ts[t] = v;
    __syncthreads();
    for (int off = 1; off < 256; off <<= 1) {
        int x = (t >= off) ? ts[t - off] : 0;
        __syncthreads();
        ts[t] += x;
        __syncthreads();
    }
    if (t < NB_SCAN) bsum[t] = ts[t] - v;
}

// ---------- scan 3 ----------
__global__ __launch_bounds__(256) void k_scan3(int* __restrict__ rp,
                                               const int* __restrict__ bsum) {
    int i = blockIdx.x * 256 + threadIdx.x;
    if (i < N_NODES) rp[i] += bsum[i / SCAN_CHUNK];
}

// ---------- bucket ----------
__global__ __launch_bounds__(256) void k_bucket(const int* __restrict__ ei,
                                                const int* __restrict__ rp,
                                                int* __restrict__ cursor,
                                                int* __restrict__ csr_src) {
    int e = blockIdx.x * 256 + threadIdx.x;
    if (e >= N_EDGES) return;
    int src = ei[e];
    int d   = ei[N_EDGES + e];
    int idx = atomicAdd(&cursor[d], 1);
    csr_src[rp[d] + idx] = src;
}

// ---------- pack 4 projection weights [128,256] -> [z][kt][nt][lane][8] bf16 ----------
__global__ __launch_bounds__(256) void pack_wg(
    const float* __restrict__ Wq, const float* __restrict__ Wk,
    const float* __restrict__ Wv, const float* __restrict__ Ws,
    unsigned short* __restrict__ Wp) {
    int i = blockIdx.x * 256 + threadIdx.x;   // 4*4*16*64 = 16384
    if (i >= 16384) return;
    int lane = i & 63, nt = (i >> 6) & 15, kt = (i >> 10) & 3, z = i >> 12;
    const float* W = (z == 0) ? Wq : (z == 1) ? Wk : (z == 2) ? Wv : Ws;
    int q = lane >> 4, c = lane & 15;
#pragma unroll
    for (int j = 0; j < 8; ++j)
        Wp[i * 8 + j] = fbf(W[(kt * 32 + q * 8 + j) * HD + nt * 16 + c]);
}

// ---------- pack W1 [512,128] into MFMA B-frag order [kt][nt][lane][8] bf16 ----------
__global__ __launch_bounds__(256) void pack_w1(const float* __restrict__ W1,
                                               unsigned short* __restrict__ W1p) {
    int i = blockIdx.x * 256 + threadIdx.x;   // 16*8*64 = 8192
    if (i >= 8192) return;
    int lane = i & 63, nt = (i >> 6) & 7, kt = i >> 9;
    int q = lane >> 4, c = lane & 15;
#pragma unroll
    for (int j = 0; j < 8; ++j)
        W1p[i * 8 + j] = fbf(W1[(kt * 32 + q * 8 + j) * 128 + nt * 16 + c]);
}

// ---------- pack W2 [128,64] -> [kt][nt][lane][8] bf16 ----------
__global__ __launch_bounds__(256) void pack_w2(const float* __restrict__ W2,
                                               unsigned short* __restrict__ W2p) {
    int i = blockIdx.x * 256 + threadIdx.x;   // 4*4*64 = 1024
    if (i >= 1024) return;
    int lane = i & 63, nt = (i >> 6) & 3, kt = i >> 8;
    int q = lane >> 4, c = lane & 15;
#pragma unroll
    for (int j = 0; j < 8; ++j)
        W2p[i * 8 + j] = fbf(W2[(kt * 32 + q * 8 + j) * 64 + nt * 16 + c]);
}

// ---------- K1: fused projection GEMM (MFMA bf16) ----------
// All four projections in one kernel. Epilogue stages each 64x256 bf16 tile
// in LDS (stride 264 breaks the row-bank alignment: 128 dw/row % 32 == 0),
// then does cooperative dwordx4 stores (16 B/lane, fully coalesced).
__global__ __launch_bounds__(256) void gemm_proj(
    const float* __restrict__ x, const float* __restrict__ mem,
    const unsigned short* __restrict__ Wp,
    const float* __restrict__ bq, const float* __restrict__ bk,
    const float* __restrict__ bv, const float* __restrict__ bs,
    unsigned short* __restrict__ Q, unsigned short* __restrict__ K,
    unsigned short* __restrict__ V, unsigned short* __restrict__ S)
{
    __shared__ __align__(16) short As[64 * 136];   // bf16(x+mem), row pad 136
    __shared__ __align__(16) short Ob[64 * 264];   // output staging, row pad 264

    const int t = threadIdx.x;
    const int w = t >> 6, l = t & 63;
    const int q = l >> 4, c = l & 15;
    const int m0 = blockIdx.x * 64;

    // stage A = bf16(x+mem)[m0..m0+64, 0..128)
    {
        const float4* x4 = (const float4*)x;
        const float4* m4 = (const float4*)mem;
#pragma unroll
        for (int j = 0; j < 8; ++j) {
            int idx = t + j * 256;       // 2048 float4 chunks
            int row = idx >> 5, c4 = idx & 31;
            int gr  = m0 + row;
            ushort4 hv = make_ushort4(0, 0, 0, 0);
            if (gr < N_NODES) {
                float4 a = x4[(size_t)gr * 32 + c4];
                float4 b = m4[(size_t)gr * 32 + c4];
                hv = make_ushort4(fbf(a.x + b.x), fbf(a.y + b.y),
                                  fbf(a.z + b.z), fbf(a.w + b.w));
            }
            *(ushort4*)&As[row * 136 + c4 * 4] = hv;
        }
    }
    __syncthreads();

    for (int z = 0; z < 4; ++z) {
        const float* bz = (z == 0) ? bq : (z == 1) ? bk : (z == 2) ? bv : bs;
        unsigned short* Oz = (z == 0) ? Q : (z == 1) ? K : (z == 2) ? V : S;

        f32x4 acc[4][4];
#pragma unroll
        for (int mt = 0; mt < 4; ++mt)
#pragma unroll
            for (int nt = 0; nt < 4; ++nt) acc[mt][nt] = (f32x4){0.f, 0.f, 0.f, 0.f};

#pragma unroll
        for (int kt = 0; kt < 4; ++kt) {
            bf16x8 af[4];
#pragma unroll
            for (int mt = 0; mt < 4; ++mt)
                af[mt] = *(const bf16x8*)&As[(mt * 16 + c) * 136 + kt * 32 + q * 8];
#pragma unroll
            for (int nt = 0; nt < 4; ++nt) {
                int ntg = w * 4 + nt;
                bf16x8 bv8 = *(const bf16x8*)&Wp[(size_t)(((z * 4 + kt) * 16 + ntg) * 64 + l) * 8];
#pragma unroll
                for (int mt = 0; mt < 4; ++mt)
                    acc[mt][nt] = __builtin_amdgcn_mfma_f32_16x16x32_bf16(af[mt], bv8, acc[mt][nt], 0, 0, 0);
            }
        }

        // epilogue: bias -> LDS staging (bank-conflict-light), then wide stores
#pragma unroll
        for (int nt = 0; nt < 4; ++nt) {
            int col = w * 64 + nt * 16 + c;
            float bb = bz[col];
#pragma unroll
            for (int mt = 0; mt < 4; ++mt)
#pragma unroll
                for (int r = 0; r < 4; ++r)
                    Ob[(mt * 16 + q * 4 + r) * 264 + col] =
                        (short)fbf(acc[mt][nt][r] + bb);
        }
        __syncthreads();
#pragma unroll
        for (int j = 0; j < 8; ++j) {
            int idx = t + j * 256;       // 2048 chunks of 16 B (64 rows x 32)
            int row = idx >> 5, ch = idx & 31;
            int gr = m0 + row;
            if (gr < N_NODES)
                *(bf16x8*)&Oz[(size_t)gr * HD + ch * 8] =
                    *(const bf16x8*)&Ob[row * 264 + ch * 8];
        }
        __syncthreads();   // Ob reused by next z
    }
}

// ---------- K2: fused attention, online softmax, one wave per node ----------
// lane l: dims 4l..4l+3 ; head = l>>4. Writes out (bf16) in-place over Q.
__global__ __launch_bounds__(256) void k_attn(
    const int* __restrict__ rp, const int* __restrict__ deg,
    const int* __restrict__ csr_src,
    const unsigned short* __restrict__ Q, const unsigned short* __restrict__ K,
    const unsigned short* __restrict__ V, const unsigned short* __restrict__ S,
    unsigned short* __restrict__ out)
{
    int node = blockIdx.x * 4 + (threadIdx.x >> 6);
    int l = threadIdx.x & 63;
    if (node >= N_NODES) return;
    int start = rp[node];
    int cnt   = deg[node];

    float q0, q1, q2, q3;
    {
        ushort4 u = *(const ushort4*)&Q[(size_t)node * HD + l * 4];
        q0 = bf2f(u.x); q1 = bf2f(u.y); q2 = bf2f(u.z); q3 = bf2f(u.w);
    }

    float m = -1e30f, d = 0.f;
    float a0 = 0.f, a1 = 0.f, a2 = 0.f, a3 = 0.f;

    for (int i = 0; i < cnt; ++i) {
        int src = csr_src[start + i];
        ushort4 ku = *(const ushort4*)&K[(size_t)src * HD + l * 4];
        float s = q0 * bf2f(ku.x) + q1 * bf2f(ku.y) + q2 * bf2f(ku.z) + q3 * bf2f(ku.w);
        s += __shfl_xor(s, 1);
        s += __shfl_xor(s, 2);
        s += __shfl_xor(s, 4);
        s += __shfl_xor(s, 8);
        s *= 0.125f;                       // 1/sqrt(64)

        float mn    = fmaxf(m, s);
        float scale = __expf(m - mn);      // first iter: exp(-huge)=0
        float e     = __expf(s - mn);
        d = d * scale + e;
        ushort4 vu = *(const ushort4*)&V[(size_t)src * HD + l * 4];
        a0 = a0 * scale + e * bf2f(vu.x);
        a1 = a1 * scale + e * bf2f(vu.y);
        a2 = a2 * scale + e * bf2f(vu.z);
        a3 = a3 * scale + e * bf2f(vu.w);
        m = mn;
    }

    float inv = 1.f / (d + 1e-16f);
    ushort4 su = *(const ushort4*)&S[(size_t)node * HD + l * 4];
    ushort4 ov = make_ushort4(fbf(bf2f(su.x) + a0 * inv),
                              fbf(bf2f(su.y) + a1 * inv),
                              fbf(bf2f(su.z) + a2 * inv),
                              fbf(bf2f(su.w) + a3 * inv));
    *(ushort4*)&out[(size_t)node * HD + l * 4] = ov;
}

// ---------- K5: MFMA rating MLP, 64 edges/block (dense bf16 out table) ----------
__global__ __launch_bounds__(256) void edge_mlp_mfma(
    const int* __restrict__ ei, const unsigned short* __restrict__ outb,
    const unsigned short* __restrict__ W1p, const float* __restrict__ b1,
    const unsigned short* __restrict__ W2p, const float* __restrict__ b2,
    const float* __restrict__ W3, const float* __restrict__ b3,
    float* __restrict__ rating)
{
    __shared__ __align__(16) char lds_raw[64 * 264 * 2];   // inter bf16 [64][264]; later h2 f32 [64][65]
    __shared__ __align__(16) short h1_s[64 * 136];
    short* inter_s = (short*)lds_raw;
    float* h2_s    = (float*)lds_raw;

    const int t = threadIdx.x;
    const int w = t >> 6, l = t & 63;
    const int q = l >> 4, c = l & 15;
    const int e0 = blockIdx.x * 64;

    f32x4 acc[8];
#pragma unroll
    for (int i = 0; i < 8; ++i) acc[i] = (f32x4){0.f, 0.f, 0.f, 0.f};

    for (int p = 0; p < 2; ++p) {
#pragma unroll
        for (int j = 0; j < 8; ++j) {
            int idx = t + j * 256;           // 2048 chunks of 16 B
            int row = idx >> 5, c4 = idx & 31;
            int node = ei[p * N_EDGES + e0 + row];
            *(bf16x8*)&inter_s[row * 264 + c4 * 8] =
                *(const bf16x8*)&outb[(size_t)node * HD + c4 * 8];
        }
        __syncthreads();
#pragma unroll
        for (int kt = 0; kt < 8; ++kt) {
            bf16x8 av = *(const bf16x8*)&inter_s[(w * 16 + c) * 264 + kt * 32 + q * 8];
#pragma unroll
            for (int nt = 0; nt < 8; ++nt) {
                bf16x8 bv = *(const bf16x8*)&W1p[(size_t)(((p * 8 + kt) * 8 + nt) * 64 + l) * 8];
                acc[nt] = __builtin_amdgcn_mfma_f32_16x16x32_bf16(av, bv, acc[nt], 0, 0, 0);
            }
        }
        __syncthreads();
    }

#pragma unroll
    for (int nt = 0; nt < 8; ++nt) {
        float bv = b1[nt * 16 + c];
#pragma unroll
        for (int r = 0; r < 4; ++r)
            h1_s[(w * 16 + q * 4 + r) * 136 + nt * 16 + c] =
                (short)fbf(fmaxf(acc[nt][r] + bv, 0.f));
    }
    __syncthreads();

    f32x4 acc2[4];
#pragma unroll
    for (int i = 0; i < 4; ++i) acc2[i] = (f32x4){0.f, 0.f, 0.f, 0.f};
#pragma unroll
    for (int kt = 0; kt < 4; ++kt) {
        bf16x8 av = *(const bf16x8*)&h1_s[(w * 16 + c) * 136 + kt * 32 + q * 8];
#pragma unroll
        for (int nt = 0; nt < 4; ++nt) {
            bf16x8 bv = *(const bf16x8*)&W2p[(size_t)((kt * 4 + nt) * 64 + l) * 8];
            acc2[nt] = __builtin_amdgcn_mfma_f32_16x16x32_bf16(av, bv, acc2[nt], 0, 0, 0);
        }
    }
    __syncthreads();

#pragma unroll
    for (int nt = 0; nt < 4; ++nt) {
        float bv = b2[nt * 16 + c];
#pragma unroll
        for (int r = 0; r < 4; ++r)
            h2_s[(w * 16 + q * 4 + r) * 65 + nt * 16 + c] = fmaxf(acc2[nt][r] + bv, 0.f);
    }
    __syncthreads();

    if (t < 64) {
        float a = b3[0];
#pragma unroll 8
        for (int kk = 0; kk < 64; ++kk)
            a += h2_s[t * 65 + kk] * W3[kk];
        rating[e0 + t] = 4.f / (1.f + __expf(-a)) + 1.f;
    }
}

extern "C" void kernel_launch(void* const* d_in, const int* in_sizes, int n_in,
                              void* d_out, int out_size, void* d_ws, size_t ws_size,
                              hipStream_t stream) {
    const int*   ei  = (const int*)d_in[0];    // [2, E]
    const float* x   = (const float*)d_in[2];
    const float* mem = (const float*)d_in[3];
    const float* Wq  = (const float*)d_in[4];
    const float* bq  = (const float*)d_in[5];
    const float* Wk  = (const float*)d_in[6];
    const float* bk  = (const float*)d_in[7];
    const float* Wv  = (const float*)d_in[8];
    const float* bv  = (const float*)d_in[9];
    const float* Ws  = (const float*)d_in[10];
    const float* bs  = (const float*)d_in[11];
    const float* W1  = (const float*)d_in[12];
    const float* b1  = (const float*)d_in[13];
    const float* W2  = (const float*)d_in[14];
    const float* b2  = (const float*)d_in[15];
    const float* W3  = (const float*)d_in[16];
    const float* b3  = (const float*)d_in[17];
    float* rating = (float*)d_out;

    // Workspace (~208 MB, under proven-safe 214 MB):
    //   Q [N,256] bf16 (becomes `out` in-place)   51.2 MB
    //   K,V,S [N,256] bf16                       153.6 MB
    //   rp, deg, cursor [N] int                    1.2 MB
    //   csr_src [E] int                            1.6 MB
    //   bsum[128]; Wp 256 KB; W1p 128 KB; W2p 16 KB
    unsigned short* Q = (unsigned short*)d_ws;
    const size_t NHDe = (size_t)N_NODES * HD;   // 25.6M elements
    unsigned short* K = Q + NHDe;
    unsigned short* V = K + NHDe;
    unsigned short* S = V + NHDe;
    int* rp      = (int*)(S + NHDe);
    int* deg     = rp + N_NODES;
    int* cursor  = deg + N_NODES;
    int* csr_src = cursor + N_NODES;
    int* bsum    = csr_src + N_EDGES;
    unsigned short* Wp  = (unsigned short*)(bsum + 128);
    unsigned short* W1p = Wp + 16384 * 8;
    unsigned short* W2p = W1p + 8192 * 8;

    const int nblk  = (N_NODES + 255) / 256;
    const int eblk  = (N_EDGES + 255) / 256;
    const int wgrid = (N_NODES + 3) / 4;

    // CSR build + weight packing
    init_zero<<<nblk, 256, 0, stream>>>(deg, cursor);
    k_deg<<<eblk, 256, 0, stream>>>(ei, deg);
    k_scan1<<<NB_SCAN, 256, 0, stream>>>(deg, rp, bsum);
    k_scan2<<<1, 256, 0, stream>>>(bsum);
    k_scan3<<<nblk, 256, 0, stream>>>(rp, bsum);
    k_bucket<<<eblk, 256, 0, stream>>>(ei, rp, cursor, csr_src);
    pack_wg<<<64, 256, 0, stream>>>(Wq, Wk, Wv, Ws, Wp);
    pack_w1<<<32, 256, 0, stream>>>(W1, W1p);
    pack_w2<<<4, 256, 0, stream>>>(W2, W2p);

    // fused projections (q/k/v/skip) -> bf16 tables
    gemm_proj<<<(N_NODES + 63) / 64, 256, 0, stream>>>(
        x, mem, Wp, bq, bk, bv, bs, Q, K, V, S);

    // fused online-softmax attention; out (bf16) overwrites Q
    k_attn<<<wgrid, 256, 0, stream>>>(rp, deg, csr_src, Q, K, V, S, Q);

    // rating MLP (MFMA) on dense bf16 out table
    edge_mlp_mfma<<<N_EDGES / 64, 256, 0, stream>>>(
        ei, Q, W1p, b1, W2p, b2, W3, b3, rating);
}